// Round 11
// baseline (1708.549 us; speedup 1.0000x reference)
//
#include <hip/hip_runtime.h>
#include <math.h>

// ---------------------------------------------------------------------------
// ConvVQVAE forward — fp32. VQ combine = VQ-VAE idiom: fl(fl(z2 + c2) - 2dot)
// (z^2 + e^2 - 2 z@e^T). Conv = im2col+OpenBLAS model: k=(ci,ky,kx) ascending
// fma chain with kc=384 panel flushes. z2/c2 = numpy pairwise. argmin =
// first-min ascending j.
//
// R16 (1704us): padded intermediates kill conv masks/cndmask.
// R17 (1630us): VQ transposed LDS tile (b128 reads) + 2-way j-split TLP.
// R18: occupancy-only change. deconv1 and conv3 sat at 4 blocks/CU (grid
// 1024); their bodies are ~93% FMA so the 39% VALU idle is latency at low
// TLP (deconv2: same FLOPs, 8 blocks/CU, faster — the controlled pair).
// COB 8->4 for both -> 2048 blocks = 8 blocks/CU = 32 waves/CU cap. COB
// only repartitions channels across threads; chains bit-identical.
// ---------------------------------------------------------------------------

// ---- zero the pad lines (row 0 and col 0) of each padded plane ------------
__global__ __launch_bounds__(256) void pad_zero_k(float* __restrict__ buf,
                                                  int HP, int WP) {
  float* p = buf + (size_t)blockIdx.x * HP * WP;
  const int tid = threadIdx.x;
  if (tid < WP) p[tid] = 0.f;                       // row 0
  if (tid >= 1 && tid < HP) p[(size_t)tid * WP] = 0.f;  // col 0 (rows 1..)
}

// ---- Conv 3x3 s2 p1, NCHW fp32, PY rows/thread, masked input (conv1) ------
template <int CIN, int COB, int PY, int LX, int ACT>
__global__ __launch_bounds__(256) void conv3x3_s2_py(
    const float* __restrict__ in, const float* __restrict__ wgt,
    float* __restrict__ out, int COUT, int HIN, int WIN, int tilesW,
    int OHP, int OWP, int po) {
  const int HOUT = HIN >> 1, WOUT = WIN >> 1;
  const int YG = 256 / LX;  // y-groups per block
  const int tid = threadIdx.x;
  const int x = (blockIdx.x % tilesW) * LX + (tid % LX);
  const int y0 = (blockIdx.x / tilesW) * (YG * PY) + (tid / LX) * PY;
  const int co0 = blockIdx.y * COB;
  const int n = blockIdx.z;
  if (x >= WOUT || y0 >= HOUT) return;

  float acc[COB][PY], sum[COB][PY];
#pragma unroll
  for (int c = 0; c < COB; ++c)
#pragma unroll
    for (int r = 0; r < PY; ++r) { acc[c][r] = 0.f; sum[c][r] = 0.f; }

  const int ix0 = 2 * x - 1;
  const int iy0 = 2 * y0 - 1;  // row j in [0, 2*PY+1): iy = iy0 + j
  for (int ci = 0; ci < CIN; ++ci) {
    const float* ip = in + (size_t)(n * CIN + ci) * HIN * WIN;
    float v[2 * PY + 1][3];
#pragma unroll
    for (int j = 0; j < 2 * PY + 1; ++j) {
      const int iy = iy0 + j;
      const bool yok = (unsigned)iy < (unsigned)HIN;
#pragma unroll
      for (int kx = 0; kx < 3; ++kx) {
        const int ix = ix0 + kx;
        v[j][kx] =
            (yok && (unsigned)ix < (unsigned)WIN) ? ip[iy * WIN + ix] : 0.f;
      }
    }
#pragma unroll
    for (int t = 0; t < 9; ++t) {
      const int kk = ci * 9 + t;  // global K index, (ci,ky,kx) ascending
      if (CIN * 9 > 384 && (kk == 384 || kk == 768)) {
        // OpenBLAS kc-panel boundary: C += panel_sum (one rounded add)
#pragma unroll
        for (int c = 0; c < COB; ++c)
#pragma unroll
          for (int r = 0; r < PY; ++r) {
            sum[c][r] = sum[c][r] + acc[c][r];
            acc[c][r] = 0.f;
          }
      }
      const int ky = t / 3, kx = t % 3;
#pragma unroll
      for (int c = 0; c < COB; ++c) {
        const float w = wgt[((size_t)(co0 + c) * CIN + ci) * 9 + t];
#pragma unroll
        for (int r = 0; r < PY; ++r)
          acc[c][r] = fmaf(v[2 * r + ky][kx], w, acc[c][r]);
      }
    }
  }
#pragma unroll
  for (int c = 0; c < COB; ++c)
#pragma unroll
    for (int r = 0; r < PY; ++r) {
      if (y0 + r < HOUT) {
        float rv = sum[c][r] + acc[c][r];  // final panel add
        if (ACT == 1) rv = fmaxf(rv, 0.f);
        out[(((size_t)n * COUT + co0 + c) * OHP + y0 + r + po) * OWP + x + po] =
            rv;
      }
    }
}

// ---- Conv 3x3 s2 p1, PADDED input, compile-time strides (conv2/conv3) -----
template <int CIN, int COB, int PY, int LX, int WINL, int ACT, int PO>
__global__ __launch_bounds__(256) void conv3x3_s2_pad(
    const float* __restrict__ in, const float* __restrict__ wgt,
    float* __restrict__ out, int COUT, int tilesW) {
  constexpr int WP = WINL + 1;            // padded stride
  constexpr int HP = WINL + 1;            // padded rows
  constexpr size_t planeP = (size_t)HP * WP;
  constexpr int HOUT = WINL >> 1, WOUT = WINL >> 1;
  constexpr int OWP = WOUT + PO;          // output stride (padded if PO)
  constexpr int OHP = HOUT + PO;
  const int YG = 256 / LX;
  const int tid = threadIdx.x;
  const int x = (blockIdx.x % tilesW) * LX + (tid % LX);
  const int y0 = (blockIdx.x / tilesW) * (YG * PY) + (tid / LX) * PY;
  const int co0 = blockIdx.y * COB;
  const int n = blockIdx.z;
  if (x >= WOUT || y0 >= HOUT) return;

  float acc[COB][PY], sum[COB][PY];
#pragma unroll
  for (int c = 0; c < COB; ++c)
#pragma unroll
    for (int r = 0; r < PY; ++r) { acc[c][r] = 0.f; sum[c][r] = 0.f; }

  // logical (iy0, ix0) = (2y0-1, 2x-1) -> padded (2y0, 2x)
  const float* bp = in + (size_t)(n * CIN) * planeP + (size_t)(2 * y0) * WP +
                    2 * x;
  for (int ci = 0; ci < CIN; ++ci, bp += planeP) {
    float v[2 * PY + 1][3];
#pragma unroll
    for (int j = 0; j < 2 * PY + 1; ++j)
#pragma unroll
      for (int kx = 0; kx < 3; ++kx) v[j][kx] = bp[j * WP + kx];
#pragma unroll
    for (int t = 0; t < 9; ++t) {
      const int kk = ci * 9 + t;  // global K index, (ci,ky,kx) ascending
      if (CIN * 9 > 384 && (kk == 384 || kk == 768)) {
        // OpenBLAS kc-panel boundary: C += panel_sum (one rounded add)
#pragma unroll
        for (int c = 0; c < COB; ++c)
#pragma unroll
          for (int r = 0; r < PY; ++r) {
            sum[c][r] = sum[c][r] + acc[c][r];
            acc[c][r] = 0.f;
          }
      }
      const int ky = t / 3, kx = t % 3;
#pragma unroll
      for (int c = 0; c < COB; ++c) {
        const float w = wgt[((size_t)(co0 + c) * CIN + ci) * 9 + t];
#pragma unroll
        for (int r = 0; r < PY; ++r)
          acc[c][r] = fmaf(v[2 * r + ky][kx], w, acc[c][r]);
      }
    }
  }
#pragma unroll
  for (int c = 0; c < COB; ++c)
#pragma unroll
    for (int r = 0; r < PY; ++r) {
      float rv = sum[c][r] + acc[c][r];  // final panel add
      if (ACT == 1) rv = fmaxf(rv, 0.f);
      out[(((size_t)n * COUT + co0 + c) * OHP + y0 + r + PO) * OWP + x + PO] =
          rv;
    }
}

// ------- ConvTranspose 3x3, stride 2, pad 1, output_pad 1, fp32 ------------
template <int CIN, int COB, int ACT>
__global__ __launch_bounds__(256) void deconv3x3_s2_quad2(
    const float* __restrict__ in, const float* __restrict__ wgt,
    float* __restrict__ out, int COUT, int HIN, int WIN, int tilesW) {
  const int HOUT = HIN * 2, WOUT = WIN * 2;
  const int tid = threadIdx.x;
  const int mx0 = ((blockIdx.x % tilesW) * 16 + (tid & 15)) * 2;
  const int my = (blockIdx.x / tilesW) * 16 + (tid >> 4);
  const int co0 = blockIdx.y * COB;
  const int n = blockIdx.z;
  if (mx0 >= WIN || my >= HIN) return;
  const bool xe = (mx0 + 2 < WIN);  // mx0+1 always < WIN (WIN even)
  const bool ye = (my + 1 < HIN);

  float accA[COB][4], accB[COB][4];
#pragma unroll
  for (int c = 0; c < COB; ++c)
#pragma unroll
    for (int q = 0; q < 4; ++q) { accA[c][q] = 0.f; accB[c][q] = 0.f; }

  const size_t plane = (size_t)HIN * WIN;
  const float* ip = in + (size_t)(n * CIN) * plane + (size_t)my * WIN + mx0;
  for (int ci = 0; ci < CIN; ++ci, ip += plane) {
    const float v00 = ip[0];
    const float v01 = ip[1];
    const float v02 = xe ? ip[2] : 0.f;
    const float v10 = ye ? ip[WIN] : 0.f;
    const float v11 = ye ? ip[WIN + 1] : 0.f;
    const float v12 = (xe && ye) ? ip[WIN + 2] : 0.f;
#pragma unroll
    for (int c = 0; c < COB; ++c) {
      const float* w = wgt + ((size_t)(co0 + c) * CIN + ci) * 9;  // uniform
      accA[c][0] = fmaf(v00, w[4], accA[c][0]);
      accA[c][1] = fmaf(v00, w[3], accA[c][1]);
      accA[c][1] = fmaf(v01, w[5], accA[c][1]);
      accA[c][2] = fmaf(v00, w[1], accA[c][2]);
      accA[c][2] = fmaf(v10, w[7], accA[c][2]);
      accA[c][3] = fmaf(v00, w[0], accA[c][3]);
      accA[c][3] = fmaf(v01, w[2], accA[c][3]);
      accA[c][3] = fmaf(v10, w[6], accA[c][3]);
      accA[c][3] = fmaf(v11, w[8], accA[c][3]);
      accB[c][0] = fmaf(v01, w[4], accB[c][0]);
      accB[c][1] = fmaf(v01, w[3], accB[c][1]);
      accB[c][1] = fmaf(v02, w[5], accB[c][1]);
      accB[c][2] = fmaf(v01, w[1], accB[c][2]);
      accB[c][2] = fmaf(v11, w[7], accB[c][2]);
      accB[c][3] = fmaf(v01, w[0], accB[c][3]);
      accB[c][3] = fmaf(v02, w[2], accB[c][3]);
      accB[c][3] = fmaf(v11, w[6], accB[c][3]);
      accB[c][3] = fmaf(v12, w[8], accB[c][3]);
    }
  }

  const int y0 = 2 * my, x0 = 2 * mx0;  // x0 % 4 == 0 -> aligned float4
#pragma unroll
  for (int c = 0; c < COB; ++c) {
    float rA[4], rB[4];
#pragma unroll
    for (int q = 0; q < 4; ++q) {
      float a = accA[c][q], b = accB[c][q];
      if (ACT == 1) { a = fmaxf(a, 0.f); b = fmaxf(b, 0.f); }
      if (ACT == 2) {
        a = 1.f / (1.f + expf(-a));
        b = 1.f / (1.f + expf(-b));
      }
      rA[q] = a; rB[q] = b;
    }
    float* op = out + (((size_t)n * COUT + co0 + c) * HOUT + y0) * WOUT + x0;
    float4 lo; lo.x = rA[0]; lo.y = rA[1]; lo.z = rB[0]; lo.w = rB[1];
    float4 hi; hi.x = rA[2]; hi.y = rA[3]; hi.z = rB[2]; hi.w = rB[3];
    *reinterpret_cast<float4*>(op) = lo;
    *reinterpret_cast<float4*>(op + WOUT) = hi;
  }
}

// --------- numpy scalar pairwise row-sum of squares, n=256, fp32 -----------
__global__ __launch_bounds__(256) void z2_np_k(const float* __restrict__ z,
                                               float* __restrict__ z2) {
#pragma clang fp contract(off)
  const int p = blockIdx.x * 256 + threadIdx.x;  // 32768
  const int n = p >> 10, hw = p & 1023;
  const float* zb = z + (size_t)n * 262144 + hw;
  float blk[2];
#pragma unroll
  for (int b = 0; b < 2; ++b) {
    float r[8];
#pragma unroll
    for (int j = 0; j < 8; ++j) {
      const float v = zb[(size_t)(b * 128 + j) * 1024];
      r[j] = v * v;
    }
    for (int i = 8; i < 128; i += 8) {
#pragma unroll
      for (int j = 0; j < 8; ++j) {
        const float v = zb[(size_t)(b * 128 + i + j) * 1024];
        const float m = v * v;
        r[j] = r[j] + m;
      }
    }
    blk[b] = ((r[0] + r[1]) + (r[2] + r[3])) + ((r[4] + r[5]) + (r[6] + r[7]));
  }
  z2[p] = blk[0] + blk[1];
}

__global__ __launch_bounds__(256) void c2_np_k(const float* __restrict__ cb,
                                               float* __restrict__ c2) {
#pragma clang fp contract(off)
  const int jrow = blockIdx.x * 256 + threadIdx.x;  // 1024
  const float* row = cb + (size_t)jrow * 256;
  float blk[2];
#pragma unroll
  for (int b = 0; b < 2; ++b) {
    float r[8];
#pragma unroll
    for (int j = 0; j < 8; ++j) {
      const float v = row[b * 128 + j];
      r[j] = v * v;
    }
    for (int i = 8; i < 128; i += 8) {
#pragma unroll
      for (int j = 0; j < 8; ++j) {
        const float v = row[b * 128 + i + j];
        const float m = v * v;
        r[j] = r[j] + m;
      }
    }
    blk[b] = ((r[0] + r[1]) + (r[2] + r[3])) + ((r[4] + r[5]) + (r[6] + r[7]));
  }
  c2[jrow] = blk[0] + blk[1];
}

// ------ VQ partial scores over a j-range: dist = fl(fl(z2+c2) - 2*dot) -----
__global__ __launch_bounds__(256) void vq_scores_part_k(
    const float* __restrict__ z, const float* __restrict__ cb,
    const float* __restrict__ z2, const float* __restrict__ c2,
    float* __restrict__ pdist, int* __restrict__ pid) {
  __shared__ float zS[32][64];  // [dim-in-chunk][pixel]
  __shared__ float cT[32][68];  // [dim-in-chunk][cw] pad->16B-aligned rows
  const int tid = threadIdx.x;
  const int p0 = blockIdx.x * 64;  // 512 px-blocks
  const int jb = blockIdx.y;       // 2 j-splits
  const int n = p0 >> 10;
  const int hw0 = p0 & 1023;
  const float* zb = z + (size_t)n * 262144 + hw0;

  const int tp = tid >> 4;  // 0..15 : pixel group (4 pixels)
  const int tj = tid & 15;  // 0..15 : codeword group (4 consecutive)

  const float4 z2q =
      *reinterpret_cast<const float4*>(&z2[p0 + tp * 4]);
  const float z2v[4] = {z2q.x, z2q.y, z2q.z, z2q.w};

  float run_d[4];
  int run_id[4];
#pragma unroll
  for (int ii = 0; ii < 4; ++ii) { run_d[ii] = 3.4e38f; run_id[ii] = 0; }

  for (int j0 = jb * 512; j0 < jb * 512 + 512; j0 += 64) {
    float acc[4][4];
#pragma unroll
    for (int a = 0; a < 4; ++a)
#pragma unroll
      for (int b = 0; b < 4; ++b) acc[a][b] = 0.f;

    for (int k0 = 0; k0 < 256; k0 += 32) {
      __syncthreads();
#pragma unroll
      for (int i = 0; i < 8; ++i) {
        const int q = i * 256 + tid;         // 0..2047
        const int zc = q >> 6, zl = q & 63;  // dim-in-chunk, pixel
        zS[zc][zl] = zb[(size_t)(k0 + zc) * 1024 + zl];
        const int cw = q >> 5, cd = q & 31;  // codeword, dim-in-chunk
        cT[cd][cw] = cb[(size_t)(j0 + cw) * 256 + k0 + cd];
      }
      __syncthreads();
#pragma unroll
      for (int d = 0; d < 32; ++d) {
        const float4 zv = *reinterpret_cast<const float4*>(&zS[d][tp * 4]);
        const float4 cv = *reinterpret_cast<const float4*>(&cT[d][tj * 4]);
        acc[0][0] = fmaf(zv.x, cv.x, acc[0][0]);
        acc[0][1] = fmaf(zv.x, cv.y, acc[0][1]);
        acc[0][2] = fmaf(zv.x, cv.z, acc[0][2]);
        acc[0][3] = fmaf(zv.x, cv.w, acc[0][3]);
        acc[1][0] = fmaf(zv.y, cv.x, acc[1][0]);
        acc[1][1] = fmaf(zv.y, cv.y, acc[1][1]);
        acc[1][2] = fmaf(zv.y, cv.z, acc[1][2]);
        acc[1][3] = fmaf(zv.y, cv.w, acc[1][3]);
        acc[2][0] = fmaf(zv.z, cv.x, acc[2][0]);
        acc[2][1] = fmaf(zv.z, cv.y, acc[2][1]);
        acc[2][2] = fmaf(zv.z, cv.z, acc[2][2]);
        acc[2][3] = fmaf(zv.z, cv.w, acc[2][3]);
        acc[3][0] = fmaf(zv.w, cv.x, acc[3][0]);
        acc[3][1] = fmaf(zv.w, cv.y, acc[3][1]);
        acc[3][2] = fmaf(zv.w, cv.z, acc[3][2]);
        acc[3][3] = fmaf(zv.w, cv.w, acc[3][3]);
      }
    }

    {
#pragma clang fp contract(off)
      const float4 c2q =
          *reinterpret_cast<const float4*>(&c2[j0 + tj * 4]);
      const float c2a[4] = {c2q.x, c2q.y, c2q.z, c2q.w};
#pragma unroll
      for (int ii = 0; ii < 4; ++ii) {
#pragma unroll
        for (int jj = 0; jj < 4; ++jj) {
          const int j = j0 + tj * 4 + jj;
          const float m2 = 2.0f * acc[ii][jj];  // exact (power of 2)
          const float t1 = z2v[ii] + c2a[jj];   // fl(A + C)  <- VQ-VAE idiom
          const float dist = t1 - m2;           // fl(T1 - B)
          if (dist < run_d[ii] || (dist == run_d[ii] && j < run_id[ii])) {
            run_d[ii] = dist;
            run_id[ii] = j;
          }
        }
      }
    }
  }

#pragma unroll
  for (int m = 1; m < 16; m <<= 1) {
#pragma unroll
    for (int ii = 0; ii < 4; ++ii) {
      const float od = __shfl_xor(run_d[ii], m, 64);
      const int oid = __shfl_xor(run_id[ii], m, 64);
      if (od < run_d[ii] || (od == run_d[ii] && oid < run_id[ii])) {
        run_d[ii] = od;
        run_id[ii] = oid;
      }
    }
  }
  if (tj == 0) {
#pragma unroll
    for (int ii = 0; ii < 4; ++ii) {
      pdist[jb * 32768 + p0 + tp * 4 + ii] = run_d[ii];
      pid[jb * 32768 + p0 + tp * 4 + ii] = run_id[ii];
    }
  }
}

// combine 2 exact partials (ascending jb; strict-less + id tie-break keeps
// first-min) then gather ids / e_k (exact fp32 gather)
__global__ __launch_bounds__(256) void vq_reduce_gather_k(
    const float* __restrict__ pdist, const int* __restrict__ pid,
    const float* __restrict__ cb, float* __restrict__ ek,
    float* __restrict__ ids) {
  const int p = blockIdx.x * 256 + threadIdx.x;  // 32768
  float bd = pdist[p];
  int bi = pid[p];
  {
    const float od = pdist[32768 + p];
    const int oi = pid[32768 + p];
    if (od < bd || (od == bd && oi < bi)) { bd = od; bi = oi; }
  }
  ids[p] = (float)bi;
  const int n = p >> 10, hw = p & 1023;
  float* ekb = ek + (size_t)n * 262144 + hw;
  const float* cbr = cb + (size_t)bi * 256;
  for (int c = 0; c < 256; ++c) ekb[(size_t)c * 1024] = cbr[c];
}

// ---------------------------------------------------------------------------
extern "C" void kernel_launch(void* const* d_in, const int* in_sizes, int n_in,
                              void* d_out, int out_size, void* d_ws,
                              size_t ws_size, hipStream_t stream) {
  const float* x = (const float*)d_in[0];
  const float* enc_w0 = (const float*)d_in[1];
  const float* enc_w1 = (const float*)d_in[2];
  const float* enc_w2 = (const float*)d_in[3];
  const float* codebook = (const float*)d_in[4];
  const float* dec_w0 = (const float*)d_in[5];
  const float* dec_w1 = (const float*)d_in[6];
  const float* dec_w2 = (const float*)d_in[7];

  float* out = (float*)d_out;          // 6,291,456
  float* z_out = out + 6291456;        // 8,388,608
  float* ek_out = z_out + 8388608;     // 8,388,608
  float* ids_out = ek_out + 8388608;   // 32,768

  // workspace layout (floats) — 129^2 = 16641:
  //   h1p @ 0          : 32*64*129*129  = 34,080,768  (padded conv1 out)
  //   h2p @ 34,080,768 : 32*128*65*65   = 17,305,600  (padded conv2 out)
  //   s   @ 51,386,368 : z2 32768 | c2 1024 | pdist 65536 | pid 65536
  // d1 aliases h2p (16.8M <= 17.3M); d2 aliases h1p (33.6M <= 34.1M).
  float* ws = (float*)d_ws;
  float* h1p = ws;
  float* h2p = ws + 34080768;
  float* d1 = h2p;
  float* d2 = h1p;
  float* s = ws + 51386368;
  float* z2 = s;                       // 32,768 f
  float* c2 = s + 32768;               //  1,024 f
  float* pdist = s + 33792;            // 65,536 f (2 x 32768)
  int* pid = (int*)(s + 99328);        // 65,536 i32

  // ---- zero pad lines of padded intermediates ----
  pad_zero_k<<<32 * 64, 256, 0, stream>>>(h1p, 129, 129);
  pad_zero_k<<<32 * 128, 256, 0, stream>>>(h2p, 65, 65);

  // ---- encoder: conv1 masked->padded out; conv2/3 padded-in unmasked ----
  conv3x3_s2_py<3, 8, 4, 16, 1><<<dim3(16, 8, 32), 256, 0, stream>>>(
      x, enc_w0, h1p, 64, 256, 256, 8, 129, 129, 1);
  conv3x3_s2_pad<64, 8, 4, 16, 128, 1, 1><<<dim3(4, 16, 32), 256, 0, stream>>>(
      h1p, enc_w1, h2p, 128, 4);
  conv3x3_s2_pad<128, 4, 4, 32, 64, 0, 0><<<dim3(1, 64, 32), 256, 0, stream>>>(
      h2p, enc_w2, z_out, 256, 1);

  // ---- VQ (fp32; dist = (z2 + c2) - 2dot; 2-way j-split, exact) ----
  z2_np_k<<<128, 256, 0, stream>>>(z_out, z2);
  c2_np_k<<<4, 256, 0, stream>>>(codebook, c2);
  vq_scores_part_k<<<dim3(512, 2), 256, 0, stream>>>(z_out, codebook, z2, c2,
                                                     pdist, pid);
  vq_reduce_gather_k<<<128, 256, 0, stream>>>(pdist, pid, codebook, ek_out,
                                              ids_out);

  // ---- decoder (fp32, parity-quad QX=2; deconv1 COB=4 for 8 blocks/CU) ----
  deconv3x3_s2_quad2<256, 4, 1><<<dim3(2, 32, 32), 256, 0, stream>>>(
      ek_out, dec_w0, d1, 128, 32, 32, 1);
  deconv3x3_s2_quad2<128, 8, 1><<<dim3(8, 8, 32), 256, 0, stream>>>(
      d1, dec_w1, d2, 64, 64, 64, 2);
  deconv3x3_s2_quad2<64, 3, 2><<<dim3(32, 1, 32), 256, 0, stream>>>(
      d2, dec_w2, out, 3, 128, 128, 4);
}

// Round 12
// 1563.635 us; speedup vs baseline: 1.0927x; 1.0927x over previous
//
#include <hip/hip_runtime.h>
#include <math.h>

// ---------------------------------------------------------------------------
// ConvVQVAE forward — fp32. VQ combine = VQ-VAE idiom: fl(fl(z2 + c2) - 2dot)
// (z^2 + e^2 - 2 z@e^T). Conv = im2col+OpenBLAS model: k=(ci,ky,kx) ascending
// fma chain with kc=384 panel flushes. z2/c2 = numpy pairwise. argmin =
// first-min ascending j.
//
// R16 (1704us): padded intermediates kill conv masks/cndmask.
// R17 (1630us): VQ transposed LDS tile (b128 reads) + 2-way j-split TLP.
// R18 REGRESSED (reverted): COB 8->4 doubled per-output overhead; occupancy
// rose 39->73% with VALUBusy flat -> deconv NOT latency-bound.
// R19: VGPR_Count evidence (28 vs >=32 live accs at COB=4; 44 vs ~80 at
// COB=8) => compiler is placing accumulators in AGPRs with accvgpr_read/
// write churn to hit its default occupancy target — explains the 1.65x
// VALU dilution (333us x 61% = 203us issue vs 123us FMA-only). Fix: pin
// __launch_bounds__(256, MINW=4) (VGPR budget 128) on conv/deconv — grids
// already provide only 4 blocks/CU, so no occupancy is lost. No arithmetic
// change -> bit-identical.
// ---------------------------------------------------------------------------

// ---- zero the pad lines (row 0 and col 0) of each padded plane ------------
__global__ __launch_bounds__(256) void pad_zero_k(float* __restrict__ buf,
                                                  int HP, int WP) {
  float* p = buf + (size_t)blockIdx.x * HP * WP;
  const int tid = threadIdx.x;
  if (tid < WP) p[tid] = 0.f;                       // row 0
  if (tid >= 1 && tid < HP) p[(size_t)tid * WP] = 0.f;  // col 0 (rows 1..)
}

// ---- Conv 3x3 s2 p1, NCHW fp32, PY rows/thread, masked input (conv1) ------
template <int CIN, int COB, int PY, int LX, int MINW, int ACT>
__global__ __launch_bounds__(256, MINW) void conv3x3_s2_py(
    const float* __restrict__ in, const float* __restrict__ wgt,
    float* __restrict__ out, int COUT, int HIN, int WIN, int tilesW,
    int OHP, int OWP, int po) {
  const int HOUT = HIN >> 1, WOUT = WIN >> 1;
  const int YG = 256 / LX;  // y-groups per block
  const int tid = threadIdx.x;
  const int x = (blockIdx.x % tilesW) * LX + (tid % LX);
  const int y0 = (blockIdx.x / tilesW) * (YG * PY) + (tid / LX) * PY;
  const int co0 = blockIdx.y * COB;
  const int n = blockIdx.z;
  if (x >= WOUT || y0 >= HOUT) return;

  float acc[COB][PY], sum[COB][PY];
#pragma unroll
  for (int c = 0; c < COB; ++c)
#pragma unroll
    for (int r = 0; r < PY; ++r) { acc[c][r] = 0.f; sum[c][r] = 0.f; }

  const int ix0 = 2 * x - 1;
  const int iy0 = 2 * y0 - 1;  // row j in [0, 2*PY+1): iy = iy0 + j
  for (int ci = 0; ci < CIN; ++ci) {
    const float* ip = in + (size_t)(n * CIN + ci) * HIN * WIN;
    float v[2 * PY + 1][3];
#pragma unroll
    for (int j = 0; j < 2 * PY + 1; ++j) {
      const int iy = iy0 + j;
      const bool yok = (unsigned)iy < (unsigned)HIN;
#pragma unroll
      for (int kx = 0; kx < 3; ++kx) {
        const int ix = ix0 + kx;
        v[j][kx] =
            (yok && (unsigned)ix < (unsigned)WIN) ? ip[iy * WIN + ix] : 0.f;
      }
    }
#pragma unroll
    for (int t = 0; t < 9; ++t) {
      const int kk = ci * 9 + t;  // global K index, (ci,ky,kx) ascending
      if (CIN * 9 > 384 && (kk == 384 || kk == 768)) {
        // OpenBLAS kc-panel boundary: C += panel_sum (one rounded add)
#pragma unroll
        for (int c = 0; c < COB; ++c)
#pragma unroll
          for (int r = 0; r < PY; ++r) {
            sum[c][r] = sum[c][r] + acc[c][r];
            acc[c][r] = 0.f;
          }
      }
      const int ky = t / 3, kx = t % 3;
#pragma unroll
      for (int c = 0; c < COB; ++c) {
        const float w = wgt[((size_t)(co0 + c) * CIN + ci) * 9 + t];
#pragma unroll
        for (int r = 0; r < PY; ++r)
          acc[c][r] = fmaf(v[2 * r + ky][kx], w, acc[c][r]);
      }
    }
  }
#pragma unroll
  for (int c = 0; c < COB; ++c)
#pragma unroll
    for (int r = 0; r < PY; ++r) {
      if (y0 + r < HOUT) {
        float rv = sum[c][r] + acc[c][r];  // final panel add
        if (ACT == 1) rv = fmaxf(rv, 0.f);
        out[(((size_t)n * COUT + co0 + c) * OHP + y0 + r + po) * OWP + x + po] =
            rv;
      }
    }
}

// ---- Conv 3x3 s2 p1, PADDED input, compile-time strides (conv2/conv3) -----
template <int CIN, int COB, int PY, int LX, int WINL, int MINW, int ACT,
          int PO>
__global__ __launch_bounds__(256, MINW) void conv3x3_s2_pad(
    const float* __restrict__ in, const float* __restrict__ wgt,
    float* __restrict__ out, int COUT, int tilesW) {
  constexpr int WP = WINL + 1;            // padded stride
  constexpr int HP = WINL + 1;            // padded rows
  constexpr size_t planeP = (size_t)HP * WP;
  constexpr int HOUT = WINL >> 1, WOUT = WINL >> 1;
  constexpr int OWP = WOUT + PO;          // output stride (padded if PO)
  constexpr int OHP = HOUT + PO;
  const int YG = 256 / LX;
  const int tid = threadIdx.x;
  const int x = (blockIdx.x % tilesW) * LX + (tid % LX);
  const int y0 = (blockIdx.x / tilesW) * (YG * PY) + (tid / LX) * PY;
  const int co0 = blockIdx.y * COB;
  const int n = blockIdx.z;
  if (x >= WOUT || y0 >= HOUT) return;

  float acc[COB][PY], sum[COB][PY];
#pragma unroll
  for (int c = 0; c < COB; ++c)
#pragma unroll
    for (int r = 0; r < PY; ++r) { acc[c][r] = 0.f; sum[c][r] = 0.f; }

  // logical (iy0, ix0) = (2y0-1, 2x-1) -> padded (2y0, 2x)
  const float* bp = in + (size_t)(n * CIN) * planeP + (size_t)(2 * y0) * WP +
                    2 * x;
  for (int ci = 0; ci < CIN; ++ci, bp += planeP) {
    float v[2 * PY + 1][3];
#pragma unroll
    for (int j = 0; j < 2 * PY + 1; ++j)
#pragma unroll
      for (int kx = 0; kx < 3; ++kx) v[j][kx] = bp[j * WP + kx];
#pragma unroll
    for (int t = 0; t < 9; ++t) {
      const int kk = ci * 9 + t;  // global K index, (ci,ky,kx) ascending
      if (CIN * 9 > 384 && (kk == 384 || kk == 768)) {
        // OpenBLAS kc-panel boundary: C += panel_sum (one rounded add)
#pragma unroll
        for (int c = 0; c < COB; ++c)
#pragma unroll
          for (int r = 0; r < PY; ++r) {
            sum[c][r] = sum[c][r] + acc[c][r];
            acc[c][r] = 0.f;
          }
      }
      const int ky = t / 3, kx = t % 3;
#pragma unroll
      for (int c = 0; c < COB; ++c) {
        const float w = wgt[((size_t)(co0 + c) * CIN + ci) * 9 + t];
#pragma unroll
        for (int r = 0; r < PY; ++r)
          acc[c][r] = fmaf(v[2 * r + ky][kx], w, acc[c][r]);
      }
    }
  }
#pragma unroll
  for (int c = 0; c < COB; ++c)
#pragma unroll
    for (int r = 0; r < PY; ++r) {
      float rv = sum[c][r] + acc[c][r];  // final panel add
      if (ACT == 1) rv = fmaxf(rv, 0.f);
      out[(((size_t)n * COUT + co0 + c) * OHP + y0 + r + PO) * OWP + x + PO] =
          rv;
    }
}

// ------- ConvTranspose 3x3, stride 2, pad 1, output_pad 1, fp32 ------------
template <int CIN, int COB, int MINW, int ACT>
__global__ __launch_bounds__(256, MINW) void deconv3x3_s2_quad2(
    const float* __restrict__ in, const float* __restrict__ wgt,
    float* __restrict__ out, int COUT, int HIN, int WIN, int tilesW) {
  const int HOUT = HIN * 2, WOUT = WIN * 2;
  const int tid = threadIdx.x;
  const int mx0 = ((blockIdx.x % tilesW) * 16 + (tid & 15)) * 2;
  const int my = (blockIdx.x / tilesW) * 16 + (tid >> 4);
  const int co0 = blockIdx.y * COB;
  const int n = blockIdx.z;
  if (mx0 >= WIN || my >= HIN) return;
  const bool xe = (mx0 + 2 < WIN);  // mx0+1 always < WIN (WIN even)
  const bool ye = (my + 1 < HIN);

  float accA[COB][4], accB[COB][4];
#pragma unroll
  for (int c = 0; c < COB; ++c)
#pragma unroll
    for (int q = 0; q < 4; ++q) { accA[c][q] = 0.f; accB[c][q] = 0.f; }

  const size_t plane = (size_t)HIN * WIN;
  const float* ip = in + (size_t)(n * CIN) * plane + (size_t)my * WIN + mx0;
  for (int ci = 0; ci < CIN; ++ci, ip += plane) {
    const float v00 = ip[0];
    const float v01 = ip[1];
    const float v02 = xe ? ip[2] : 0.f;
    const float v10 = ye ? ip[WIN] : 0.f;
    const float v11 = ye ? ip[WIN + 1] : 0.f;
    const float v12 = (xe && ye) ? ip[WIN + 2] : 0.f;
#pragma unroll
    for (int c = 0; c < COB; ++c) {
      const float* w = wgt + ((size_t)(co0 + c) * CIN + ci) * 9;  // uniform
      accA[c][0] = fmaf(v00, w[4], accA[c][0]);
      accA[c][1] = fmaf(v00, w[3], accA[c][1]);
      accA[c][1] = fmaf(v01, w[5], accA[c][1]);
      accA[c][2] = fmaf(v00, w[1], accA[c][2]);
      accA[c][2] = fmaf(v10, w[7], accA[c][2]);
      accA[c][3] = fmaf(v00, w[0], accA[c][3]);
      accA[c][3] = fmaf(v01, w[2], accA[c][3]);
      accA[c][3] = fmaf(v10, w[6], accA[c][3]);
      accA[c][3] = fmaf(v11, w[8], accA[c][3]);
      accB[c][0] = fmaf(v01, w[4], accB[c][0]);
      accB[c][1] = fmaf(v01, w[3], accB[c][1]);
      accB[c][1] = fmaf(v02, w[5], accB[c][1]);
      accB[c][2] = fmaf(v01, w[1], accB[c][2]);
      accB[c][2] = fmaf(v11, w[7], accB[c][2]);
      accB[c][3] = fmaf(v01, w[0], accB[c][3]);
      accB[c][3] = fmaf(v02, w[2], accB[c][3]);
      accB[c][3] = fmaf(v11, w[6], accB[c][3]);
      accB[c][3] = fmaf(v12, w[8], accB[c][3]);
    }
  }

  const int y0 = 2 * my, x0 = 2 * mx0;  // x0 % 4 == 0 -> aligned float4
#pragma unroll
  for (int c = 0; c < COB; ++c) {
    float rA[4], rB[4];
#pragma unroll
    for (int q = 0; q < 4; ++q) {
      float a = accA[c][q], b = accB[c][q];
      if (ACT == 1) { a = fmaxf(a, 0.f); b = fmaxf(b, 0.f); }
      if (ACT == 2) {
        a = 1.f / (1.f + expf(-a));
        b = 1.f / (1.f + expf(-b));
      }
      rA[q] = a; rB[q] = b;
    }
    float* op = out + (((size_t)n * COUT + co0 + c) * HOUT + y0) * WOUT + x0;
    float4 lo; lo.x = rA[0]; lo.y = rA[1]; lo.z = rB[0]; lo.w = rB[1];
    float4 hi; hi.x = rA[2]; hi.y = rA[3]; hi.z = rB[2]; hi.w = rB[3];
    *reinterpret_cast<float4*>(op) = lo;
    *reinterpret_cast<float4*>(op + WOUT) = hi;
  }
}

// --------- numpy scalar pairwise row-sum of squares, n=256, fp32 -----------
__global__ __launch_bounds__(256) void z2_np_k(const float* __restrict__ z,
                                               float* __restrict__ z2) {
#pragma clang fp contract(off)
  const int p = blockIdx.x * 256 + threadIdx.x;  // 32768
  const int n = p >> 10, hw = p & 1023;
  const float* zb = z + (size_t)n * 262144 + hw;
  float blk[2];
#pragma unroll
  for (int b = 0; b < 2; ++b) {
    float r[8];
#pragma unroll
    for (int j = 0; j < 8; ++j) {
      const float v = zb[(size_t)(b * 128 + j) * 1024];
      r[j] = v * v;
    }
    for (int i = 8; i < 128; i += 8) {
#pragma unroll
      for (int j = 0; j < 8; ++j) {
        const float v = zb[(size_t)(b * 128 + i + j) * 1024];
        const float m = v * v;
        r[j] = r[j] + m;
      }
    }
    blk[b] = ((r[0] + r[1]) + (r[2] + r[3])) + ((r[4] + r[5]) + (r[6] + r[7]));
  }
  z2[p] = blk[0] + blk[1];
}

__global__ __launch_bounds__(256) void c2_np_k(const float* __restrict__ cb,
                                               float* __restrict__ c2) {
#pragma clang fp contract(off)
  const int jrow = blockIdx.x * 256 + threadIdx.x;  // 1024
  const float* row = cb + (size_t)jrow * 256;
  float blk[2];
#pragma unroll
  for (int b = 0; b < 2; ++b) {
    float r[8];
#pragma unroll
    for (int j = 0; j < 8; ++j) {
      const float v = row[b * 128 + j];
      r[j] = v * v;
    }
    for (int i = 8; i < 128; i += 8) {
#pragma unroll
      for (int j = 0; j < 8; ++j) {
        const float v = row[b * 128 + i + j];
        const float m = v * v;
        r[j] = r[j] + m;
      }
    }
    blk[b] = ((r[0] + r[1]) + (r[2] + r[3])) + ((r[4] + r[5]) + (r[6] + r[7]));
  }
  c2[jrow] = blk[0] + blk[1];
}

// ------ VQ partial scores over a j-range: dist = fl(fl(z2+c2) - 2*dot) -----
__global__ __launch_bounds__(256) void vq_scores_part_k(
    const float* __restrict__ z, const float* __restrict__ cb,
    const float* __restrict__ z2, const float* __restrict__ c2,
    float* __restrict__ pdist, int* __restrict__ pid) {
  __shared__ float zS[32][64];  // [dim-in-chunk][pixel]
  __shared__ float cT[32][68];  // [dim-in-chunk][cw] pad->16B-aligned rows
  const int tid = threadIdx.x;
  const int p0 = blockIdx.x * 64;  // 512 px-blocks
  const int jb = blockIdx.y;       // 2 j-splits
  const int n = p0 >> 10;
  const int hw0 = p0 & 1023;
  const float* zb = z + (size_t)n * 262144 + hw0;

  const int tp = tid >> 4;  // 0..15 : pixel group (4 pixels)
  const int tj = tid & 15;  // 0..15 : codeword group (4 consecutive)

  const float4 z2q =
      *reinterpret_cast<const float4*>(&z2[p0 + tp * 4]);
  const float z2v[4] = {z2q.x, z2q.y, z2q.z, z2q.w};

  float run_d[4];
  int run_id[4];
#pragma unroll
  for (int ii = 0; ii < 4; ++ii) { run_d[ii] = 3.4e38f; run_id[ii] = 0; }

  for (int j0 = jb * 512; j0 < jb * 512 + 512; j0 += 64) {
    float acc[4][4];
#pragma unroll
    for (int a = 0; a < 4; ++a)
#pragma unroll
      for (int b = 0; b < 4; ++b) acc[a][b] = 0.f;

    for (int k0 = 0; k0 < 256; k0 += 32) {
      __syncthreads();
#pragma unroll
      for (int i = 0; i < 8; ++i) {
        const int q = i * 256 + tid;         // 0..2047
        const int zc = q >> 6, zl = q & 63;  // dim-in-chunk, pixel
        zS[zc][zl] = zb[(size_t)(k0 + zc) * 1024 + zl];
        const int cw = q >> 5, cd = q & 31;  // codeword, dim-in-chunk
        cT[cd][cw] = cb[(size_t)(j0 + cw) * 256 + k0 + cd];
      }
      __syncthreads();
#pragma unroll
      for (int d = 0; d < 32; ++d) {
        const float4 zv = *reinterpret_cast<const float4*>(&zS[d][tp * 4]);
        const float4 cv = *reinterpret_cast<const float4*>(&cT[d][tj * 4]);
        acc[0][0] = fmaf(zv.x, cv.x, acc[0][0]);
        acc[0][1] = fmaf(zv.x, cv.y, acc[0][1]);
        acc[0][2] = fmaf(zv.x, cv.z, acc[0][2]);
        acc[0][3] = fmaf(zv.x, cv.w, acc[0][3]);
        acc[1][0] = fmaf(zv.y, cv.x, acc[1][0]);
        acc[1][1] = fmaf(zv.y, cv.y, acc[1][1]);
        acc[1][2] = fmaf(zv.y, cv.z, acc[1][2]);
        acc[1][3] = fmaf(zv.y, cv.w, acc[1][3]);
        acc[2][0] = fmaf(zv.z, cv.x, acc[2][0]);
        acc[2][1] = fmaf(zv.z, cv.y, acc[2][1]);
        acc[2][2] = fmaf(zv.z, cv.z, acc[2][2]);
        acc[2][3] = fmaf(zv.z, cv.w, acc[2][3]);
        acc[3][0] = fmaf(zv.w, cv.x, acc[3][0]);
        acc[3][1] = fmaf(zv.w, cv.y, acc[3][1]);
        acc[3][2] = fmaf(zv.w, cv.z, acc[3][2]);
        acc[3][3] = fmaf(zv.w, cv.w, acc[3][3]);
      }
    }

    {
#pragma clang fp contract(off)
      const float4 c2q =
          *reinterpret_cast<const float4*>(&c2[j0 + tj * 4]);
      const float c2a[4] = {c2q.x, c2q.y, c2q.z, c2q.w};
#pragma unroll
      for (int ii = 0; ii < 4; ++ii) {
#pragma unroll
        for (int jj = 0; jj < 4; ++jj) {
          const int j = j0 + tj * 4 + jj;
          const float m2 = 2.0f * acc[ii][jj];  // exact (power of 2)
          const float t1 = z2v[ii] + c2a[jj];   // fl(A + C)  <- VQ-VAE idiom
          const float dist = t1 - m2;           // fl(T1 - B)
          if (dist < run_d[ii] || (dist == run_d[ii] && j < run_id[ii])) {
            run_d[ii] = dist;
            run_id[ii] = j;
          }
        }
      }
    }
  }

#pragma unroll
  for (int m = 1; m < 16; m <<= 1) {
#pragma unroll
    for (int ii = 0; ii < 4; ++ii) {
      const float od = __shfl_xor(run_d[ii], m, 64);
      const int oid = __shfl_xor(run_id[ii], m, 64);
      if (od < run_d[ii] || (od == run_d[ii] && oid < run_id[ii])) {
        run_d[ii] = od;
        run_id[ii] = oid;
      }
    }
  }
  if (tj == 0) {
#pragma unroll
    for (int ii = 0; ii < 4; ++ii) {
      pdist[jb * 32768 + p0 + tp * 4 + ii] = run_d[ii];
      pid[jb * 32768 + p0 + tp * 4 + ii] = run_id[ii];
    }
  }
}

// combine 2 exact partials (ascending jb; strict-less + id tie-break keeps
// first-min) then gather ids / e_k (exact fp32 gather)
__global__ __launch_bounds__(256) void vq_reduce_gather_k(
    const float* __restrict__ pdist, const int* __restrict__ pid,
    const float* __restrict__ cb, float* __restrict__ ek,
    float* __restrict__ ids) {
  const int p = blockIdx.x * 256 + threadIdx.x;  // 32768
  float bd = pdist[p];
  int bi = pid[p];
  {
    const float od = pdist[32768 + p];
    const int oi = pid[32768 + p];
    if (od < bd || (od == bd && oi < bi)) { bd = od; bi = oi; }
  }
  ids[p] = (float)bi;
  const int n = p >> 10, hw = p & 1023;
  float* ekb = ek + (size_t)n * 262144 + hw;
  const float* cbr = cb + (size_t)bi * 256;
  for (int c = 0; c < 256; ++c) ekb[(size_t)c * 1024] = cbr[c];
}

// ---------------------------------------------------------------------------
extern "C" void kernel_launch(void* const* d_in, const int* in_sizes, int n_in,
                              void* d_out, int out_size, void* d_ws,
                              size_t ws_size, hipStream_t stream) {
  const float* x = (const float*)d_in[0];
  const float* enc_w0 = (const float*)d_in[1];
  const float* enc_w1 = (const float*)d_in[2];
  const float* enc_w2 = (const float*)d_in[3];
  const float* codebook = (const float*)d_in[4];
  const float* dec_w0 = (const float*)d_in[5];
  const float* dec_w1 = (const float*)d_in[6];
  const float* dec_w2 = (const float*)d_in[7];

  float* out = (float*)d_out;          // 6,291,456
  float* z_out = out + 6291456;        // 8,388,608
  float* ek_out = z_out + 8388608;     // 8,388,608
  float* ids_out = ek_out + 8388608;   // 32,768

  // workspace layout (floats) — 129^2 = 16641:
  //   h1p @ 0          : 32*64*129*129  = 34,080,768  (padded conv1 out)
  //   h2p @ 34,080,768 : 32*128*65*65   = 17,305,600  (padded conv2 out)
  //   s   @ 51,386,368 : z2 32768 | c2 1024 | pdist 65536 | pid 65536
  // d1 aliases h2p (16.8M <= 17.3M); d2 aliases h1p (33.6M <= 34.1M).
  float* ws = (float*)d_ws;
  float* h1p = ws;
  float* h2p = ws + 34080768;
  float* d1 = h2p;
  float* d2 = h1p;
  float* s = ws + 51386368;
  float* z2 = s;                       // 32,768 f
  float* c2 = s + 32768;               //  1,024 f
  float* pdist = s + 33792;            // 65,536 f (2 x 32768)
  int* pid = (int*)(s + 99328);        // 65,536 i32

  // ---- zero pad lines of padded intermediates ----
  pad_zero_k<<<32 * 64, 256, 0, stream>>>(h1p, 129, 129);
  pad_zero_k<<<32 * 128, 256, 0, stream>>>(h2p, 65, 65);

  // ---- encoder: conv1 masked->padded out; conv2/3 padded-in unmasked ----
  conv3x3_s2_py<3, 8, 4, 16, 4, 1><<<dim3(16, 8, 32), 256, 0, stream>>>(
      x, enc_w0, h1p, 64, 256, 256, 8, 129, 129, 1);
  conv3x3_s2_pad<64, 8, 4, 16, 128, 4, 1, 1>
      <<<dim3(4, 16, 32), 256, 0, stream>>>(h1p, enc_w1, h2p, 128, 4);
  conv3x3_s2_pad<128, 8, 4, 32, 64, 4, 0, 0>
      <<<dim3(1, 32, 32), 256, 0, stream>>>(h2p, enc_w2, z_out, 256, 1);

  // ---- VQ (fp32; dist = (z2 + c2) - 2dot; 2-way j-split, exact) ----
  z2_np_k<<<128, 256, 0, stream>>>(z_out, z2);
  c2_np_k<<<4, 256, 0, stream>>>(codebook, c2);
  vq_scores_part_k<<<dim3(512, 2), 256, 0, stream>>>(z_out, codebook, z2, c2,
                                                     pdist, pid);
  vq_reduce_gather_k<<<128, 256, 0, stream>>>(pdist, pid, codebook, ek_out,
                                              ids_out);

  // ---- decoder (fp32, parity-quad QX=2; R17 grids + MINW=4) ----
  deconv3x3_s2_quad2<256, 8, 4, 1><<<dim3(2, 16, 32), 256, 0, stream>>>(
      ek_out, dec_w0, d1, 128, 32, 32, 1);
  deconv3x3_s2_quad2<128, 8, 4, 1><<<dim3(8, 8, 32), 256, 0, stream>>>(
      d1, dec_w1, d2, 64, 64, 64, 2);
  deconv3x3_s2_quad2<64, 3, 4, 2><<<dim3(32, 1, 32), 256, 0, stream>>>(
      d2, dec_w2, out, 3, 128, 128, 4);
}